// Round 16
// baseline (98.126 us; speedup 1.0000x reference)
//
#include <hip/hip_runtime.h>
#include <hip/hip_bf16.h>
#include <stdint.h>

#define B_   1024
#define NN_  64
#define F_   128
#define DM_  512
#define DK_  256

typedef unsigned short u16;
using f32x4  = __attribute__((ext_vector_type(4))) float;
using bf16x8 = __attribute__((ext_vector_type(8))) short;

__device__ __forceinline__ uint32_t f2bf(float x) {
  uint32_t u = __builtin_bit_cast(uint32_t, x);
  return (u + 0x7fffu + ((u >> 16) & 1u)) >> 16;  // RNE bf16
}
__device__ __forceinline__ float bf2f(uint32_t us) {
  return __builtin_bit_cast(float, us << 16);
}
__device__ __forceinline__ void split_pack(float x, float y, uint32_t& hp, uint32_t& lp) {
  uint32_t hx = f2bf(x), hy = f2bf(y);
  uint32_t lx = f2bf(x - bf2f(hx)), ly = f2bf(y - bf2f(hy));
  hp = hx | (hy << 16);
  lp = lx | (ly << 16);
}
__device__ __forceinline__ void split1(float x, u16& h, u16& l) {
  uint32_t hx = f2bf(x);
  h = (u16)hx;
  l = (u16)f2bf(x - bf2f(hx));
}
// DPP adds on the VALU pipe; CTRL compile-time constant.
template <int CTRL>
__device__ __forceinline__ float dppadd(float x) {
  int r = __builtin_amdgcn_mov_dpp(__builtin_bit_cast(int, x), CTRL, 0xF, 0xF, true);
  return x + __builtin_bit_cast(float, r);
}
__device__ __forceinline__ float red16(float p) {
  p = dppadd<0xB1>(p);   // quad_perm xor 1
  p = dppadd<0x4E>(p);   // quad_perm xor 2
  p = dppadd<0x114>(p);  // row_shr:4
  p = dppadd<0x118>(p);  // row_shr:8
  return p;              // lanes 12,28,44,60 hold their 16-lane-group sums
}

// ---------------- K0: weight splits + wv transpose + wkc fold (merged) ----------------
__global__ __launch_bounds__(256) void k_prep(
    const float* __restrict__ wv, const float* __restrict__ fc_w,
    const float* __restrict__ m1_w, const float* __restrict__ m2_w,
    const float* __restrict__ wk, const float* __restrict__ wm,
    u16* __restrict__ fc_hi, u16* __restrict__ fc_lo,
    u16* __restrict__ wvT_hi, u16* __restrict__ wvT_lo,
    u16* __restrict__ m1_hi, u16* __restrict__ m1_lo,
    u16* __restrict__ m2_hi, u16* __restrict__ m2_lo,
    float* __restrict__ wkc) {
  __shared__ float tile[32][33];
  int tid = threadIdx.x;
  int bx = blockIdx.x;

  if (bx >= 256) {  // wkc fold: 16 blocks
    int t = bx - 256;
    int h = t >> 3, dc = t & 7;
    int w = tid >> 6, l = tid & 63;
    int d = dc * 64 + l;
    const float* base = wk + (size_t)(h * DK_ + w * 64) * DM_ + d;
    float sacc[8] = {0.f, 0.f, 0.f, 0.f, 0.f, 0.f, 0.f, 0.f};
    #pragma unroll
    for (int e = 0; e < 64; ++e)
      sacc[e & 7] += base[e * DM_] * wm[DK_ + w * 64 + e];
    float s = ((sacc[0] + sacc[1]) + (sacc[2] + sacc[3])) +
              ((sacc[4] + sacc[5]) + (sacc[6] + sacc[7]));
    float* part = &tile[0][0];
    part[w * 64 + l] = s;
    __syncthreads();
    if (w == 0)
      wkc[h * DM_ + d] = part[l] + part[64 + l] + part[128 + l] + part[192 + l];
    return;
  }

  int gtid = bx * 256 + tid;
  int nthr = 256 * 256;
  for (int i = gtid; i < DM_ * DM_; i += nthr) split1(fc_w[i], fc_hi[i], fc_lo[i]);
  for (int i = gtid; i < F_ * (DM_ + F_); i += nthr) split1(m1_w[i], m1_hi[i], m1_lo[i]);
  for (int i = gtid; i < F_ * F_; i += nthr) split1(m2_w[i], m2_hi[i], m2_lo[i]);

  int e0 = (bx >> 4) * 32, d0 = (bx & 15) * 32;
  int rr = tid >> 3, c4 = (tid & 7) * 4;
  float4 v = *(const float4*)(wv + (e0 + rr) * DM_ + d0 + c4);
  tile[rr][c4] = v.x; tile[rr][c4 + 1] = v.y;
  tile[rr][c4 + 2] = v.z; tile[rr][c4 + 3] = v.w;
  __syncthreads();
  int dr = tid >> 3, ec = (tid & 7) * 4;
  #pragma unroll
  for (int q = 0; q < 4; ++q) {
    int idx = (d0 + dr) * DM_ + e0 + ec + q;
    split1(tile[ec + q][dr], wvT_hi[idx], wvT_lo[idx]);
  }
}

// ------- split-bf16 MFMA tile -------
__device__ __forceinline__ f32x4 mfma_tile_split(
    const u16* __restrict__ Ahi, const u16* __restrict__ Alo, int lda,
    const u16* __restrict__ Bhi, const u16* __restrict__ Blo, int ldb, int K) {
  int l = threadIdx.x & 63;
  int r = l & 15, g = l >> 4;
  int offA = r * lda + g * 8;
  int offB = r * ldb + g * 8;
  f32x4 acc = {0.f, 0.f, 0.f, 0.f};
  for (int k = 0; k < K; k += 32) {
    bf16x8 ah = *(const bf16x8*)(Ahi + offA + k);
    bf16x8 al = *(const bf16x8*)(Alo + offA + k);
    bf16x8 bh = *(const bf16x8*)(Bhi + offB + k);
    bf16x8 bl = *(const bf16x8*)(Blo + offB + k);
    acc = __builtin_amdgcn_mfma_f32_16x16x32_bf16(ah, bh, acc, 0, 0, 0);
    acc = __builtin_amdgcn_mfma_f32_16x16x32_bf16(ah, bl, acc, 0, 0, 0);
    acc = __builtin_amdgcn_mfma_f32_16x16x32_bf16(al, bh, acc, 0, 0, 0);
  }
  return acc;
}

// ---------------- K0c: Wcomb ----------------
__global__ __launch_bounds__(256) void k_wcomb(
    const u16* __restrict__ fc_hi, const u16* __restrict__ fc_lo,
    const u16* __restrict__ wvT_hi, const u16* __restrict__ wvT_lo,
    u16* __restrict__ wc_hi, u16* __restrict__ wc_lo) {
  int wid = threadIdx.x >> 6;
  int n0g = blockIdx.y * 32;
  int h = n0g >> 9, d0 = n0g & 511;
  int m0 = blockIdx.x * 32 + (wid >> 1) * 16;
  int nb = d0 + (wid & 1) * 16;
  f32x4 acc = mfma_tile_split(fc_hi + m0 * DM_ + h * DK_,
                              fc_lo + m0 * DM_ + h * DK_, DM_,
                              wvT_hi + nb * DM_ + h * DK_,
                              wvT_lo + nb * DM_ + h * DK_, DM_, DK_);
  int l = threadIdx.x & 63, r = l & 15, g = l >> 4;
  #pragma unroll
  for (int i = 0; i < 4; ++i) {
    int m = m0 + g * 4 + i;
    int idx = m * 1024 + n0g + (wid & 1) * 16 + r;
    split1(acc[i], wc_hi[idx], wc_lo[idx]);
  }
}

// ---------------- K1a v2: streaming score partials, batched loads, no shfl ----------------
// grid (1024, 4): b, array w. Wave ww owns rows [16ww,16ww+16).
// Lane = (r16 = l>>4, c16 = l&15): 16 lanes per row, c16 owns floats [8c16, 8c16+8).
// All 8 float4 loads per thread batch-issued; reduction = pure DPP red16.
__global__ __launch_bounds__(256) void k_score(
    const float* __restrict__ seq, const float* __restrict__ seq_e,
    const float* __restrict__ seq_t, const float* __restrict__ seq_p,
    const float* __restrict__ wkc, float* __restrict__ S_part) {
  int b = blockIdx.x, w = blockIdx.y;
  int tid = threadIdx.x;
  int ww = tid >> 6, l = tid & 63;
  int r16 = l >> 4, c16 = l & 15;
  const float* arr = (w == 0 ? seq : (w == 1 ? seq_e : (w == 2 ? seq_t : seq_p)));
  int cb = 8 * c16;
  float c0[8], c1[8];
  #pragma unroll
  for (int u = 0; u < 8; ++u) {
    c0[u] = wkc[w * 128 + cb + u];
    c1[u] = wkc[512 + w * 128 + cb + u];
  }
  const float* base = arr + (size_t)b * 8192 + (size_t)(ww * 16 + r16) * 128 + cb;
  size_t s0i = (((size_t)w * 1024 + b) * 2 + 0) * 64;
  size_t s1i = (((size_t)w * 1024 + b) * 2 + 1) * 64;

  // batch-issue all 8 independent loads (rows ww*16 + i*4 + r16, i=0..3)
  float4 va[4], vb[4];
  #pragma unroll
  for (int i = 0; i < 4; ++i) {
    va[i] = *(const float4*)(base + i * 512);
    vb[i] = *(const float4*)(base + i * 512 + 4);
  }
  #pragma unroll
  for (int i = 0; i < 4; ++i) {
    float p0 = va[i].x * c0[0] + va[i].y * c0[1] + va[i].z * c0[2] + va[i].w * c0[3]
             + vb[i].x * c0[4] + vb[i].y * c0[5] + vb[i].z * c0[6] + vb[i].w * c0[7];
    float p1 = va[i].x * c1[0] + va[i].y * c1[1] + va[i].z * c1[2] + va[i].w * c1[3]
             + vb[i].x * c1[4] + vb[i].y * c1[5] + vb[i].z * c1[6] + vb[i].w * c1[7];
    p0 = red16(p0);
    p1 = red16(p1);
    if (c16 == 12) {
      int r = ww * 16 + i * 4 + r16;
      S_part[s0i + r] = p0;
      S_part[s1i + r] = p1;
    }
  }
}

// ---------------- K1b v2: softmax + kbar, batched column loads ----------------
__global__ __launch_bounds__(256) void k_attn2(
    const float* __restrict__ seq, const float* __restrict__ seq_e,
    const float* __restrict__ seq_t, const float* __restrict__ seq_p,
    const int* __restrict__ mask, const float* __restrict__ S_part,
    float* __restrict__ attn_out,
    uint32_t* __restrict__ kbar_hi, uint32_t* __restrict__ kbar_lo) {
  __shared__ float attns[2][64];
  int tid = threadIdx.x, b = blockIdx.x;

  if (tid < 128) {  // softmax: waves 0,1 = heads 0,1; lane = row
    int h = tid >> 6, row = tid & 63;
    float s = 0.f;
    #pragma unroll
    for (int w4 = 0; w4 < 4; ++w4)
      s += S_part[(((size_t)w4 * 1024 + b) * 2 + h) * 64 + row];
    if (mask[b * 64 + row]) s = -1e10f;
    float m = s;
    #pragma unroll
    for (int off = 32; off; off >>= 1) m = fmaxf(m, __shfl_xor(m, off));
    float p = expf(s - m);
    float ssum = p;
    #pragma unroll
    for (int off = 32; off; off >>= 1) ssum += __shfl_xor(ssum, off);
    float a = p / ssum;
    attns[h][row] = a;
    attn_out[(h * B_ + b) * 64 + row] = a;
  }
  __syncthreads();

  // kbar: thread = (array part, d-pair); loads batched 8 deep
  int part = tid >> 6, dp = tid & 63;
  const float* colp =
      (part == 0 ? seq : (part == 1 ? seq_e : (part == 2 ? seq_t : seq_p))) +
      (size_t)b * 8192 + 2 * dp;
  float a00 = 0.f, a01 = 0.f, a10 = 0.f, a11 = 0.f;
  #pragma unroll
  for (int jb = 0; jb < 64; jb += 8) {
    float2 v[8];
    #pragma unroll
    for (int u = 0; u < 8; ++u)
      v[u] = *(const float2*)(colp + (jb + u) * 128);
    #pragma unroll
    for (int u = 0; u < 8; ++u) {
      int j = jb + u;
      float t0 = attns[0][j], t1 = attns[1][j];
      a00 += t0 * v[u].x; a01 += t0 * v[u].y;
      a10 += t1 * v[u].x; a11 += t1 * v[u].y;
    }
  }
  uint32_t hp, lp;
  int idx = b * 512 + tid;  // u16 layout = [b][h*512+d]
  split_pack(a00, a01, hp, lp);
  kbar_hi[idx] = hp; kbar_lo[idx] = lp;
  split_pack(a10, a11, hp, lp);
  kbar_hi[idx + 256] = hp; kbar_lo[idx + 256] = lp;
}

// ---------------- K2: fco = LeakyReLU(kbar·Wcomb^T + b) + q  (fp32) ----------------
__global__ __launch_bounds__(256) void k_fc(
    const u16* __restrict__ kb_hi, const u16* __restrict__ kb_lo,
    const u16* __restrict__ wc_hi, const u16* __restrict__ wc_lo,
    const float* __restrict__ fc_b,
    const float* __restrict__ src, const float* __restrict__ src_t,
    const float* __restrict__ src_p, float* __restrict__ fco) {
  int tid = threadIdx.x;
  int wid = tid >> 6, l = tid & 63;
  int r = l & 15, g = l >> 4;
  int m0 = blockIdx.x * 32 + (wid >> 1) * 16;
  int n0 = blockIdx.y * 64 + (wid & 1) * 32;
  int offA  = (m0 + r) * 1024 + g * 8;
  int offB0 = (n0 + r) * 1024 + g * 8;
  int offB1 = offB0 + 16 * 1024;
  f32x4 acc0 = {0.f, 0.f, 0.f, 0.f}, acc1 = {0.f, 0.f, 0.f, 0.f};
  #pragma unroll 4
  for (int k = 0; k < 1024; k += 32) {
    bf16x8 ah  = *(const bf16x8*)(kb_hi + offA + k);
    bf16x8 al  = *(const bf16x8*)(kb_lo + offA + k);
    bf16x8 b0h = *(const bf16x8*)(wc_hi + offB0 + k);
    bf16x8 b0l = *(const bf16x8*)(wc_lo + offB0 + k);
    bf16x8 b1h = *(const bf16x8*)(wc_hi + offB1 + k);
    bf16x8 b1l = *(const bf16x8*)(wc_lo + offB1 + k);
    acc0 = __builtin_amdgcn_mfma_f32_16x16x32_bf16(ah, b0h, acc0, 0, 0, 0);
    acc0 = __builtin_amdgcn_mfma_f32_16x16x32_bf16(ah, b0l, acc0, 0, 0, 0);
    acc0 = __builtin_amdgcn_mfma_f32_16x16x32_bf16(al, b0h, acc0, 0, 0, 0);
    acc1 = __builtin_amdgcn_mfma_f32_16x16x32_bf16(ah, b1h, acc1, 0, 0, 0);
    acc1 = __builtin_amdgcn_mfma_f32_16x16x32_bf16(ah, b1l, acc1, 0, 0, 0);
    acc1 = __builtin_amdgcn_mfma_f32_16x16x32_bf16(al, b1h, acc1, 0, 0, 0);
  }
  #pragma unroll
  for (int f = 0; f < 2; ++f) {
    int col = n0 + f * 16 + r;
    int part = col >> 7, fc2 = col & 127;
    float bias = fc_b[col];
    const float* qsrc = (part == 0 ? src : (part == 2 ? src_t : src_p));
    #pragma unroll
    for (int i = 0; i < 4; ++i) {
      int m = m0 + g * 4 + i;
      float c = (f == 0 ? acc0[i] : acc1[i]) + bias;
      c = (c >= 0.f) ? c : 0.2f * c;  // LeakyReLU(0.2)
      float qv = (part == 1) ? 0.f : qsrc[m * 128 + fc2];
      fco[m * 512 + col] = c + qv;
    }
  }
}

// ---------------- K3: LN (in-block) + m1(relu) + m2 fused ----------------
// grid 64 x 512 threads; block owns 16 rows.
__global__ __launch_bounds__(512) void k_m12(
    const float* __restrict__ fco, const float* __restrict__ ln_g,
    const float* __restrict__ ln_b, const float* __restrict__ src,
    const u16* __restrict__ m1_hi, const u16* __restrict__ m1_lo,
    const float* __restrict__ m1_b,
    const u16* __restrict__ m2_hi, const u16* __restrict__ m2_lo,
    const float* __restrict__ m2_b, float* __restrict__ z) {
  __shared__ u16 xh[16][648], xl[16][648];  // lda 648: 2-way-free b128 reads
  __shared__ u16 hh[16][136], hl[16][136];
  int tid = threadIdx.x;
  int m0 = blockIdx.x * 16;

  // phase A: LayerNorm + build x = [ln_out, src] (rows: tid>>5, 32 lanes/row)
  {
    int row = tid >> 5, l32 = tid & 31;
    int grow = m0 + row;
    float v[16];
    float s = 0.f, s2 = 0.f;
    #pragma unroll
    for (int q = 0; q < 16; ++q) {
      v[q] = fco[grow * 512 + q * 32 + l32];
      s += v[q]; s2 += v[q] * v[q];
    }
    #pragma unroll
    for (int off = 16; off; off >>= 1) {
      s += __shfl_xor(s, off, 32);
      s2 += __shfl_xor(s2, off, 32);
    }
    float mu = s * (1.f / 512.f);
    float var = s2 * (1.f / 512.f) - mu * mu;
    float rstd = rsqrtf(var + 1e-5f);
    #pragma unroll
    for (int q = 0; q < 16; ++q) {
      int col = q * 32 + l32;
      float o = (v[q] - mu) * rstd * ln_g[col] + ln_b[col];
      split1(o, xh[row][col], xl[row][col]);
    }
    #pragma unroll
    for (int q2 = 0; q2 < 4; ++q2) {
      int c = q2 * 32 + l32;
      split1(src[grow * 128 + c], xh[row][512 + c], xl[row][512 + c]);
    }
  }
  __syncthreads();

  // phase B: hdn = relu(x·m1^T + b1) -> LDS
  int wid = tid >> 6, l = tid & 63;
  int r = l & 15, g = l >> 4;
  int nb = wid * 16;
  {
    f32x4 acc = mfma_tile_split(&xh[0][0], &xl[0][0], 648,
                                m1_hi + nb * 640, m1_lo + nb * 640, 640, 640);
    int col = nb + r;
    float bias = m1_b[col];
    #pragma unroll
    for (int ii = 0; ii < 4; ++ii) {
      int row = g * 4 + ii;
      float o = fmaxf(acc[ii] + bias, 0.f);
      split1(o, hh[row][col], hl[row][col]);
    }
  }
  __syncthreads();

  // phase C: z = hdn·m2^T + b2
  {
    f32x4 acc = mfma_tile_split(&hh[0][0], &hl[0][0], 136,
                                m2_hi + nb * 128, m2_lo + nb * 128, 128, 128);
    int col = nb + r;
    float bias = m2_b[col];
    #pragma unroll
    for (int ii = 0; ii < 4; ++ii) {
      int row = g * 4 + ii;
      z[(m0 + row) * 128 + col] = acc[ii] + bias;
    }
  }
}

extern "C" void kernel_launch(void* const* d_in, const int* in_sizes, int n_in,
                              void* d_out, int out_size, void* d_ws, size_t ws_size,
                              hipStream_t stream) {
  (void)in_sizes; (void)n_in; (void)out_size; (void)ws_size;
  const float* src   = (const float*)d_in[0];
  const float* src_t = (const float*)d_in[1];
  const float* src_p = (const float*)d_in[2];
  const float* seq   = (const float*)d_in[3];
  const float* seq_t = (const float*)d_in[4];
  const float* seq_e = (const float*)d_in[5];
  const float* seq_p = (const float*)d_in[6];
  const int*   mask  = (const int*)d_in[7];  // int32 on device (proven r1-3)
  // d_in[8] = wq : unused (score_q cancels in softmax)
  const float* wk   = (const float*)d_in[9];
  const float* wv   = (const float*)d_in[10];
  const float* wm   = (const float*)d_in[11];
  const float* fc_w = (const float*)d_in[12];
  const float* fc_b = (const float*)d_in[13];
  const float* ln_g = (const float*)d_in[14];
  const float* ln_b = (const float*)d_in[15];
  const float* m1_w = (const float*)d_in[16];
  const float* m1_b = (const float*)d_in[17];
  const float* m2_w = (const float*)d_in[18];
  const float* m2_b = (const float*)d_in[19];

  float* z_out    = (float*)d_out;
  float* attn_out = z_out + B_ * F_;

  char* ws = (char*)d_ws;
  float* wkc     = (float*)(ws + 0);           //    4096
  u16* fc_hi     = (u16*)(ws + 4096);          //  524288
  u16* fc_lo     = (u16*)(ws + 528384);        //  524288
  u16* m1_hi     = (u16*)(ws + 1052672);       //  163840
  u16* m1_lo     = (u16*)(ws + 1216512);       //  163840
  u16* m2_hi     = (u16*)(ws + 1380352);       //   32768
  u16* m2_lo     = (u16*)(ws + 1413120);       //   32768
  u16* wvT_hi    = (u16*)(ws + 1445888);       //  524288
  u16* wvT_lo    = (u16*)(ws + 1970176);       //  524288
  u16* wc_hi     = (u16*)(ws + 2494464);       // 1048576
  u16* wc_lo     = (u16*)(ws + 3543040);       // 1048576
  uint32_t* kbhi = (uint32_t*)(ws + 4591616);  // 2097152
  uint32_t* kblo = (uint32_t*)(ws + 6688768);  // 2097152
  float* fco     = (float*)(ws + 8785920);     // 2097152
  float* S_part  = (float*)(ws + 10883072);    // 2097152  (4*1024*2*64 f32)

  hipLaunchKernelGGL(k_prep, dim3(272), dim3(256), 0, stream,
                     wv, fc_w, m1_w, m2_w, wk, wm,
                     fc_hi, fc_lo, wvT_hi, wvT_lo,
                     m1_hi, m1_lo, m2_hi, m2_lo, wkc);
  hipLaunchKernelGGL(k_score, dim3(1024, 4), dim3(256), 0, stream,
                     seq, seq_e, seq_t, seq_p, wkc, S_part);
  hipLaunchKernelGGL(k_attn2, dim3(1024), dim3(256), 0, stream,
                     seq, seq_e, seq_t, seq_p, mask, S_part,
                     attn_out, kbhi, kblo);
  hipLaunchKernelGGL(k_wcomb, dim3(16, 32), dim3(256), 0, stream,
                     fc_hi, fc_lo, wvT_hi, wvT_lo, wc_hi, wc_lo);
  hipLaunchKernelGGL(k_fc, dim3(32, 8), dim3(256), 0, stream,
                     (const u16*)kbhi, (const u16*)kblo, wc_hi, wc_lo, fc_b,
                     src, src_t, src_p, fco);
  hipLaunchKernelGGL(k_m12, dim3(64), dim3(512), 0, stream,
                     fco, ln_g, ln_b, src,
                     m1_hi, m1_lo, m1_b, m2_hi, m2_lo, m2_b, z_out);
}

// Round 18
// 80.714 us; speedup vs baseline: 1.2157x; 1.2157x over previous
//
#include <hip/hip_runtime.h>
#include <hip/hip_bf16.h>
#include <stdint.h>

#define B_   1024
#define NN_  64
#define F_   128
#define DM_  512
#define DK_  256

typedef unsigned short u16;
using f32x4  = __attribute__((ext_vector_type(4))) float;
using bf16x8 = __attribute__((ext_vector_type(8))) short;

__device__ __forceinline__ uint32_t f2bf(float x) {
  uint32_t u = __builtin_bit_cast(uint32_t, x);
  return (u + 0x7fffu + ((u >> 16) & 1u)) >> 16;  // RNE bf16
}
__device__ __forceinline__ float bf2f(uint32_t us) {
  return __builtin_bit_cast(float, us << 16);
}
__device__ __forceinline__ void split_pack(float x, float y, uint32_t& hp, uint32_t& lp) {
  uint32_t hx = f2bf(x), hy = f2bf(y);
  uint32_t lx = f2bf(x - bf2f(hx)), ly = f2bf(y - bf2f(hy));
  hp = hx | (hy << 16);
  lp = lx | (ly << 16);
}
__device__ __forceinline__ void split1(float x, u16& h, u16& l) {
  uint32_t hx = f2bf(x);
  h = (u16)hx;
  l = (u16)f2bf(x - bf2f(hx));
}
// DPP adds on the VALU pipe; CTRL compile-time constant.
template <int CTRL>
__device__ __forceinline__ float dppadd(float x) {
  int r = __builtin_amdgcn_mov_dpp(__builtin_bit_cast(int, x), CTRL, 0xF, 0xF, true);
  return x + __builtin_bit_cast(float, r);
}
__device__ __forceinline__ float red16(float p) {
  p = dppadd<0xB1>(p);   // quad_perm xor 1
  p = dppadd<0x4E>(p);   // quad_perm xor 2
  p = dppadd<0x114>(p);  // row_shr:4
  p = dppadd<0x118>(p);  // row_shr:8
  return p;              // lanes 12,28,44,60 hold their 16-lane-group sums
}

// ---------------- K0: weight splits + wv transpose + wkc fold (merged) ----------------
__global__ __launch_bounds__(256) void k_prep(
    const float* __restrict__ wv, const float* __restrict__ fc_w,
    const float* __restrict__ m1_w, const float* __restrict__ m2_w,
    const float* __restrict__ wk, const float* __restrict__ wm,
    u16* __restrict__ fc_hi, u16* __restrict__ fc_lo,
    u16* __restrict__ wvT_hi, u16* __restrict__ wvT_lo,
    u16* __restrict__ m1_hi, u16* __restrict__ m1_lo,
    u16* __restrict__ m2_hi, u16* __restrict__ m2_lo,
    float* __restrict__ wkc) {
  __shared__ float tile[32][33];
  int tid = threadIdx.x;
  int bx = blockIdx.x;

  if (bx >= 256) {  // wkc fold: 16 blocks
    int t = bx - 256;
    int h = t >> 3, dc = t & 7;
    int w = tid >> 6, l = tid & 63;
    int d = dc * 64 + l;
    const float* base = wk + (size_t)(h * DK_ + w * 64) * DM_ + d;
    float sacc[8] = {0.f, 0.f, 0.f, 0.f, 0.f, 0.f, 0.f, 0.f};
    #pragma unroll
    for (int e = 0; e < 64; ++e)
      sacc[e & 7] += base[e * DM_] * wm[DK_ + w * 64 + e];
    float s = ((sacc[0] + sacc[1]) + (sacc[2] + sacc[3])) +
              ((sacc[4] + sacc[5]) + (sacc[6] + sacc[7]));
    float* part = &tile[0][0];
    part[w * 64 + l] = s;
    __syncthreads();
    if (w == 0)
      wkc[h * DM_ + d] = part[l] + part[64 + l] + part[128 + l] + part[192 + l];
    return;
  }

  int gtid = bx * 256 + tid;
  int nthr = 256 * 256;
  for (int i = gtid; i < DM_ * DM_; i += nthr) split1(fc_w[i], fc_hi[i], fc_lo[i]);
  for (int i = gtid; i < F_ * (DM_ + F_); i += nthr) split1(m1_w[i], m1_hi[i], m1_lo[i]);
  for (int i = gtid; i < F_ * F_; i += nthr) split1(m2_w[i], m2_hi[i], m2_lo[i]);

  int e0 = (bx >> 4) * 32, d0 = (bx & 15) * 32;
  int rr = tid >> 3, c4 = (tid & 7) * 4;
  float4 v = *(const float4*)(wv + (e0 + rr) * DM_ + d0 + c4);
  tile[rr][c4] = v.x; tile[rr][c4 + 1] = v.y;
  tile[rr][c4 + 2] = v.z; tile[rr][c4 + 3] = v.w;
  __syncthreads();
  int dr = tid >> 3, ec = (tid & 7) * 4;
  #pragma unroll
  for (int q = 0; q < 4; ++q) {
    int idx = (d0 + dr) * DM_ + e0 + ec + q;
    split1(tile[ec + q][dr], wvT_hi[idx], wvT_lo[idx]);
  }
}

// ------- split-bf16 MFMA tile -------
__device__ __forceinline__ f32x4 mfma_tile_split(
    const u16* __restrict__ Ahi, const u16* __restrict__ Alo, int lda,
    const u16* __restrict__ Bhi, const u16* __restrict__ Blo, int ldb, int K) {
  int l = threadIdx.x & 63;
  int r = l & 15, g = l >> 4;
  int offA = r * lda + g * 8;
  int offB = r * ldb + g * 8;
  f32x4 acc = {0.f, 0.f, 0.f, 0.f};
  for (int k = 0; k < K; k += 32) {
    bf16x8 ah = *(const bf16x8*)(Ahi + offA + k);
    bf16x8 al = *(const bf16x8*)(Alo + offA + k);
    bf16x8 bh = *(const bf16x8*)(Bhi + offB + k);
    bf16x8 bl = *(const bf16x8*)(Blo + offB + k);
    acc = __builtin_amdgcn_mfma_f32_16x16x32_bf16(ah, bh, acc, 0, 0, 0);
    acc = __builtin_amdgcn_mfma_f32_16x16x32_bf16(ah, bl, acc, 0, 0, 0);
    acc = __builtin_amdgcn_mfma_f32_16x16x32_bf16(al, bh, acc, 0, 0, 0);
  }
  return acc;
}

// ---------------- K0c: Wcomb ----------------
__global__ __launch_bounds__(256) void k_wcomb(
    const u16* __restrict__ fc_hi, const u16* __restrict__ fc_lo,
    const u16* __restrict__ wvT_hi, const u16* __restrict__ wvT_lo,
    u16* __restrict__ wc_hi, u16* __restrict__ wc_lo) {
  int wid = threadIdx.x >> 6;
  int n0g = blockIdx.y * 32;
  int h = n0g >> 9, d0 = n0g & 511;
  int m0 = blockIdx.x * 32 + (wid >> 1) * 16;
  int nb = d0 + (wid & 1) * 16;
  f32x4 acc = mfma_tile_split(fc_hi + m0 * DM_ + h * DK_,
                              fc_lo + m0 * DM_ + h * DK_, DM_,
                              wvT_hi + nb * DM_ + h * DK_,
                              wvT_lo + nb * DM_ + h * DK_, DM_, DK_);
  int l = threadIdx.x & 63, r = l & 15, g = l >> 4;
  #pragma unroll
  for (int i = 0; i < 4; ++i) {
    int m = m0 + g * 4 + i;
    int idx = m * 1024 + n0g + (wid & 1) * 16 + r;
    split1(acc[i], wc_hi[idx], wc_lo[idx]);
  }
}

// ---------------- K1: fused single-pass attn (no max-subtraction) ----------------
// Per block b: thread = (array w = tid>>6, d-pair l = tid&63).
// 8 batches x 8 rows: batched float2 loads -> dot partials -> DPP red16 ->
// e=exp(s) (16-thread finalize) -> kbar += e*v from registers. Normalize at end.
__global__ __launch_bounds__(256) void k_attn(
    const float* __restrict__ seq, const float* __restrict__ seq_e,
    const float* __restrict__ seq_t, const float* __restrict__ seq_p,
    const int* __restrict__ mask, const float* __restrict__ wkc,
    float* __restrict__ attn_out,
    uint32_t* __restrict__ kbar_hi, uint32_t* __restrict__ kbar_lo) {
  __shared__ float pbuf[4][2][8][4];  // [wave][head][row-in-batch][group16]
  __shared__ float els[2][64];        // e = exp(s), 0 if masked
  __shared__ float Zs[2];
  int tid = threadIdx.x, b = blockIdx.x;
  int w = tid >> 6, l = tid & 63;
  int c16 = l & 15;

  const float* arr = (w == 0 ? seq : (w == 1 ? seq_e : (w == 2 ? seq_t : seq_p)));
  const float* base = arr + (size_t)b * 8192 + 2 * l;
  float c00 = wkc[w * 128 + 2 * l],       c01 = wkc[w * 128 + 2 * l + 1];
  float c10 = wkc[512 + w * 128 + 2 * l], c11 = wkc[512 + w * 128 + 2 * l + 1];
  float kb00 = 0.f, kb01 = 0.f, kb10 = 0.f, kb11 = 0.f;

  for (int bt = 0; bt < 8; ++bt) {
    float2 v[8];
    #pragma unroll
    for (int u = 0; u < 8; ++u)
      v[u] = *(const float2*)(base + (size_t)(bt * 8 + u) * 128);
    #pragma unroll
    for (int u = 0; u < 8; ++u) {
      float p0 = v[u].x * c00 + v[u].y * c01;
      float p1 = v[u].x * c10 + v[u].y * c11;
      p0 = red16(p0);
      p1 = red16(p1);
      if (c16 == 12) {
        pbuf[w][0][u][l >> 4] = p0;
        pbuf[w][1][u][l >> 4] = p1;
      }
    }
    __syncthreads();
    if (tid < 16) {  // finalize 16 scores: 8 rows x 2 heads
      int u = tid & 7, h = tid >> 3;
      float s = 0.f;
      #pragma unroll
      for (int ww = 0; ww < 4; ++ww)
        #pragma unroll
        for (int g = 0; g < 4; ++g) s += pbuf[ww][h][u][g];
      int row = bt * 8 + u;
      els[h][row] = mask[b * 64 + row] ? 0.f : expf(s);
    }
    __syncthreads();
    #pragma unroll
    for (int u = 0; u < 8; ++u) {
      int row = bt * 8 + u;
      float e0 = els[0][row], e1 = els[1][row];
      kb00 += e0 * v[u].x; kb01 += e0 * v[u].y;
      kb10 += e1 * v[u].x; kb11 += e1 * v[u].y;
    }
  }

  // Z per head; attn output; kbar normalize+write
  if (tid < 128) {
    int h = tid >> 6, row = tid & 63;
    float e = els[h][row];
    float z = e;
    #pragma unroll
    for (int off = 32; off; off >>= 1) z += __shfl_xor(z, off);
    attn_out[(h * B_ + b) * 64 + row] = e / z;
    if (row == 0) Zs[h] = z;
  }
  __syncthreads();
  float r0 = 1.f / Zs[0], r1 = 1.f / Zs[1];
  uint32_t hp, lp;
  int idx = b * 512 + tid;  // u16 layout = [b][h*512+d]
  split_pack(kb00 * r0, kb01 * r0, hp, lp);
  kbar_hi[idx] = hp; kbar_lo[idx] = lp;
  split_pack(kb10 * r1, kb11 * r1, hp, lp);
  kbar_hi[idx + 256] = hp; kbar_lo[idx + 256] = lp;
}

// ---------------- K2: fco = LeakyReLU(kbar·Wcomb^T + b) + q  (fp32) ----------------
// grid (32,8); 4 waves (2m x 2n); output cols = nn = 512 (K dim is 1024!)
__global__ __launch_bounds__(256) void k_fc(
    const u16* __restrict__ kb_hi, const u16* __restrict__ kb_lo,
    const u16* __restrict__ wc_hi, const u16* __restrict__ wc_lo,
    const float* __restrict__ fc_b,
    const float* __restrict__ src, const float* __restrict__ src_t,
    const float* __restrict__ src_p, float* __restrict__ fco) {
  int tid = threadIdx.x;
  int wid = tid >> 6, l = tid & 63;
  int r = l & 15, g = l >> 4;
  int m0 = blockIdx.x * 32 + (wid >> 1) * 16;
  int n0 = blockIdx.y * 64 + (wid & 1) * 32;
  int offA  = (m0 + r) * 1024 + g * 8;
  int offB0 = (n0 + r) * 1024 + g * 8;
  int offB1 = offB0 + 16 * 1024;
  f32x4 acc0 = {0.f, 0.f, 0.f, 0.f}, acc1 = {0.f, 0.f, 0.f, 0.f};
  #pragma unroll 4
  for (int k = 0; k < 1024; k += 32) {
    bf16x8 ah  = *(const bf16x8*)(kb_hi + offA + k);
    bf16x8 al  = *(const bf16x8*)(kb_lo + offA + k);
    bf16x8 b0h = *(const bf16x8*)(wc_hi + offB0 + k);
    bf16x8 b0l = *(const bf16x8*)(wc_lo + offB0 + k);
    bf16x8 b1h = *(const bf16x8*)(wc_hi + offB1 + k);
    bf16x8 b1l = *(const bf16x8*)(wc_lo + offB1 + k);
    acc0 = __builtin_amdgcn_mfma_f32_16x16x32_bf16(ah, b0h, acc0, 0, 0, 0);
    acc0 = __builtin_amdgcn_mfma_f32_16x16x32_bf16(ah, b0l, acc0, 0, 0, 0);
    acc0 = __builtin_amdgcn_mfma_f32_16x16x32_bf16(al, b0h, acc0, 0, 0, 0);
    acc1 = __builtin_amdgcn_mfma_f32_16x16x32_bf16(ah, b1h, acc1, 0, 0, 0);
    acc1 = __builtin_amdgcn_mfma_f32_16x16x32_bf16(ah, b1l, acc1, 0, 0, 0);
    acc1 = __builtin_amdgcn_mfma_f32_16x16x32_bf16(al, b1h, acc1, 0, 0, 0);
  }
  #pragma unroll
  for (int f = 0; f < 2; ++f) {
    int col = n0 + f * 16 + r;
    int part = col >> 7, fc2 = col & 127;
    float bias = fc_b[col];
    const float* qsrc = (part == 0 ? src : (part == 2 ? src_t : src_p));
    #pragma unroll
    for (int i = 0; i < 4; ++i) {
      int m = m0 + g * 4 + i;
      float c = (f == 0 ? acc0[i] : acc1[i]) + bias;
      c = (c >= 0.f) ? c : 0.2f * c;  // LeakyReLU(0.2)
      float qv = (part == 1) ? 0.f : qsrc[m * 128 + fc2];
      fco[m * 512 + col] = c + qv;
    }
  }
}

// ---------------- K3: LN (in-block) + m1(relu) + m2 fused ----------------
__global__ __launch_bounds__(512) void k_m12(
    const float* __restrict__ fco, const float* __restrict__ ln_g,
    const float* __restrict__ ln_b, const float* __restrict__ src,
    const u16* __restrict__ m1_hi, const u16* __restrict__ m1_lo,
    const float* __restrict__ m1_b,
    const u16* __restrict__ m2_hi, const u16* __restrict__ m2_lo,
    const float* __restrict__ m2_b, float* __restrict__ z) {
  __shared__ u16 xh[16][648], xl[16][648];
  __shared__ u16 hh[16][136], hl[16][136];
  int tid = threadIdx.x;
  int m0 = blockIdx.x * 16;

  {
    int row = tid >> 5, l32 = tid & 31;
    int grow = m0 + row;
    float v[16];
    float s = 0.f, s2 = 0.f;
    #pragma unroll
    for (int q = 0; q < 16; ++q) {
      v[q] = fco[grow * 512 + q * 32 + l32];
      s += v[q]; s2 += v[q] * v[q];
    }
    #pragma unroll
    for (int off = 16; off; off >>= 1) {
      s += __shfl_xor(s, off, 32);
      s2 += __shfl_xor(s2, off, 32);
    }
    float mu = s * (1.f / 512.f);
    float var = s2 * (1.f / 512.f) - mu * mu;
    float rstd = rsqrtf(var + 1e-5f);
    #pragma unroll
    for (int q = 0; q < 16; ++q) {
      int col = q * 32 + l32;
      float o = (v[q] - mu) * rstd * ln_g[col] + ln_b[col];
      split1(o, xh[row][col], xl[row][col]);
    }
    #pragma unroll
    for (int q2 = 0; q2 < 4; ++q2) {
      int c = q2 * 32 + l32;
      split1(src[grow * 128 + c], xh[row][512 + c], xl[row][512 + c]);
    }
  }
  __syncthreads();

  int wid = tid >> 6, l = tid & 63;
  int r = l & 15, g = l >> 4;
  int nb = wid * 16;
  {
    f32x4 acc = mfma_tile_split(&xh[0][0], &xl[0][0], 648,
                                m1_hi + nb * 640, m1_lo + nb * 640, 640, 640);
    int col = nb + r;
    float bias = m1_b[col];
    #pragma unroll
    for (int ii = 0; ii < 4; ++ii) {
      int row = g * 4 + ii;
      float o = fmaxf(acc[ii] + bias, 0.f);
      split1(o, hh[row][col], hl[row][col]);
    }
  }
  __syncthreads();
  {
    f32x4 acc = mfma_tile_split(&hh[0][0], &hl[0][0], 136,
                                m2_hi + nb * 128, m2_lo + nb * 128, 128, 128);
    int col = nb + r;
    float bias = m2_b[col];
    #pragma unroll
    for (int ii = 0; ii < 4; ++ii) {
      int row = g * 4 + ii;
      z[(m0 + row) * 128 + col] = acc[ii] + bias;
    }
  }
}

extern "C" void kernel_launch(void* const* d_in, const int* in_sizes, int n_in,
                              void* d_out, int out_size, void* d_ws, size_t ws_size,
                              hipStream_t stream) {
  (void)in_sizes; (void)n_in; (void)out_size; (void)ws_size;
  const float* src   = (const float*)d_in[0];
  const float* src_t = (const float*)d_in[1];
  const float* src_p = (const float*)d_in[2];
  const float* seq   = (const float*)d_in[3];
  const float* seq_t = (const float*)d_in[4];
  const float* seq_e = (const float*)d_in[5];
  const float* seq_p = (const float*)d_in[6];
  const int*   mask  = (const int*)d_in[7];  // int32 on device (proven r1-3)
  // d_in[8] = wq : unused (score_q cancels in softmax)
  const float* wk   = (const float*)d_in[9];
  const float* wv   = (const float*)d_in[10];
  const float* wm   = (const float*)d_in[11];
  const float* fc_w = (const float*)d_in[12];
  const float* fc_b = (const float*)d_in[13];
  const float* ln_g = (const float*)d_in[14];
  const float* ln_b = (const float*)d_in[15];
  const float* m1_w = (const float*)d_in[16];
  const float* m1_b = (const float*)d_in[17];
  const float* m2_w = (const float*)d_in[18];
  const float* m2_b = (const float*)d_in[19];

  float* z_out    = (float*)d_out;
  float* attn_out = z_out + B_ * F_;

  char* ws = (char*)d_ws;
  float* wkc     = (float*)(ws + 0);           //    4096
  u16* fc_hi     = (u16*)(ws + 4096);          //  524288
  u16* fc_lo     = (u16*)(ws + 528384);        //  524288
  u16* m1_hi     = (u16*)(ws + 1052672);       //  163840
  u16* m1_lo     = (u16*)(ws + 1216512);       //  163840
  u16* m2_hi     = (u16*)(ws + 1380352);       //   32768
  u16* m2_lo     = (u16*)(ws + 1413120);       //   32768
  u16* wvT_hi    = (u16*)(ws + 1445888);       //  524288
  u16* wvT_lo    = (u16*)(ws + 1970176);       //  524288
  u16* wc_hi     = (u16*)(ws + 2494464);       // 1048576
  u16* wc_lo     = (u16*)(ws + 3543040);       // 1048576
  uint32_t* kbhi = (uint32_t*)(ws + 4591616);  // 2097152
  uint32_t* kblo = (uint32_t*)(ws + 6688768);  // 2097152
  float* fco     = (float*)(ws + 8785920);     // 2097152

  hipLaunchKernelGGL(k_prep, dim3(272), dim3(256), 0, stream,
                     wv, fc_w, m1_w, m2_w, wk, wm,
                     fc_hi, fc_lo, wvT_hi, wvT_lo,
                     m1_hi, m1_lo, m2_hi, m2_lo, wkc);
  hipLaunchKernelGGL(k_attn, dim3(1024), dim3(256), 0, stream,
                     seq, seq_e, seq_t, seq_p, mask, wkc,
                     attn_out, kbhi, kblo);
  hipLaunchKernelGGL(k_wcomb, dim3(16, 32), dim3(256), 0, stream,
                     fc_hi, fc_lo, wvT_hi, wvT_lo, wc_hi, wc_lo);
  hipLaunchKernelGGL(k_fc, dim3(32, 8), dim3(256), 0, stream,
                     (const u16*)kbhi, (const u16*)kblo, wc_hi, wc_lo, fc_b,
                     src, src_t, src_p, fco);
  hipLaunchKernelGGL(k_m12, dim3(64), dim3(512), 0, stream,
                     fco, ln_g, ln_b, src,
                     m1_hi, m1_lo, m1_b, m2_hi, m2_lo, m2_b, z_out);
}